// Round 13
// baseline (397.444 us; speedup 1.0000x reference)
//
#include <hip/hip_runtime.h>
#include <hip/hip_cooperative_groups.h>
#include <hip/hip_bf16.h>
#include <math.h>

namespace cg = cooperative_groups;

#define BB 64
#define NN 256
#define D_VIS 2048
#define D_LBL 512
#define HH 8
#define FF 256
#define DG 2048
#define DE 512
#define ALPHA 0.2f
#define PSTRIDE 264

using bf16 = __hip_bfloat16;
using short8 = __attribute__((ext_vector_type(8))) short;
using f32x4  = __attribute__((ext_vector_type(4))) float;
__device__ __forceinline__ float b2f(bf16 x) { return __bfloat162float(x); }
__device__ __forceinline__ unsigned short f2bs(float x) {
    bf16 h = __float2bfloat16(x);
    unsigned short u;
    __builtin_memcpy(&u, &h, 2);
    return u;
}

// One cooperative kernel: S1 Wh-GEMM -> sync -> S2 GAT(b-loop) -> sync ->
// S3a pool(+bias) -> sync -> S3b fc. 256 blocks x 512 threads (1 block/CU).
__global__ void __launch_bounds__(512) k_mega(
        const float* __restrict__ labels, const float* __restrict__ visual,
        const float* __restrict__ Wg, const float* __restrict__ adj,
        const float* __restrict__ aSrc, const float* __restrict__ aDst,
        const float* __restrict__ pool_q, const float* __restrict__ fcW,
        const float* __restrict__ fcb, float* __restrict__ out,
        unsigned short* __restrict__ WhLbT, float* __restrict__ WhVz,
        float* __restrict__ srcLp, float* __restrict__ dstLp,
        float* __restrict__ srcVp, float* __restrict__ dstVp,
        float* __restrict__ ps_p, float* __restrict__ pooled,
        bf16* __restrict__ outb) {
    cg::grid_group grid = cg::this_grid();
    const int bid = blockIdx.x;
    const int t = threadIdx.x;

    __shared__ __align__(16) union SharedU {
        struct { unsigned short As[2][32][72], Bs[2][64][72]; } s1;
        struct { unsigned short Pl[64][PSTRIDE]; float dls2[2 * NN];
                 float esl[64], easl[64], ensl[64], inv[64], cb[8];
                 unsigned int maskB[64][8]; } s2;
        struct { float wsm[2][NN], redm[2][4], reds[2][4]; } s3;
        struct { unsigned short As[32][136], Bs[64][136]; } s4;
    } sh;

    // ================= S1: Wh GEMM (2 units per block) =================
    {
        const int half = t >> 8;
        const int tt = t & 255;
        const int u = 2 * bid + half;        // 0..511
        const int xb = u & 31;
        const int y  = u >> 5;               // 0..15
        const int w4 = tt >> 6;
        const int lane = tt & 63;
        const int l15 = lane & 15, quad = lane >> 4;
        const int n0 = xb * 64;
        const int p2 = xb & 3;
        const bool isL = (y < 8);
        const int q = y - 8;
        const int m0  = isL ? y * 32 : (q & 1) * 32;
        const int z   = isL ? 0 : (q >> 1);
        const int kb0 = z * 512;
        const float* A = isL ? labels : visual;
        const int lda  = isL ? D_LBL : D_VIS;
        const float* Wb = Wg + (isL ? 0 : (size_t)D_LBL * DG);

        f32x4 acc[2];
        acc[0] = (f32x4){0.f, 0.f, 0.f, 0.f};
        acc[1] = (f32x4){0.f, 0.f, 0.f, 0.f};
        for (int kc = 0; kc < 8; ++kc) {
            const int kb = kb0 + kc * 64;
#pragma unroll
            for (int p = 0; p < 2; ++p) {
                const int idx = tt + 256 * p;
                const int r = idx >> 4, q4 = idx & 15;
                const float4 v = *(const float4*)(A + (size_t)(m0 + r) * lda + kb + 4 * q4);
                unsigned short s4v[4] = {f2bs(v.x), f2bs(v.y), f2bs(v.z), f2bs(v.w)};
                __builtin_memcpy(&sh.s1.As[half][r][4 * q4], s4v, 8);
            }
#pragma unroll
            for (int p = 0; p < 4; ++p) {
                const int kk = (tt >> 4) + 16 * p;
                const int c4 = (tt & 15) * 4;
                const float4 v = *(const float4*)(Wb + (size_t)(kb + kk) * DG + n0 + c4);
                sh.s1.Bs[half][c4 + 0][kk] = f2bs(v.x);
                sh.s1.Bs[half][c4 + 1][kk] = f2bs(v.y);
                sh.s1.Bs[half][c4 + 2][kk] = f2bs(v.z);
                sh.s1.Bs[half][c4 + 3][kk] = f2bs(v.w);
            }
            __syncthreads();
#pragma unroll
            for (int ks = 0; ks < 2; ++ks) {
                const short8 bf = *(const short8*)&sh.s1.Bs[half][w4 * 16 + l15][ks * 32 + quad * 8];
#pragma unroll
                for (int mi = 0; mi < 2; ++mi) {
                    const short8 af = *(const short8*)&sh.s1.As[half][mi * 16 + l15][ks * 32 + quad * 8];
                    acc[mi] = __builtin_amdgcn_mfma_f32_16x16x32_bf16(af, bf, acc[mi], 0, 0, 0);
                }
            }
            __syncthreads();
        }
        const int col = n0 + w4 * 16 + l15;
        const int h = col >> 8;
        const float as = aSrc[col], ad = aDst[col];
        if (isL) {
#pragma unroll
            for (int mi = 0; mi < 2; ++mi) {
                unsigned short s4v[4];
#pragma unroll
                for (int r = 0; r < 4; ++r) s4v[r] = f2bs(acc[mi][r]);
                __builtin_memcpy(&WhLbT[(size_t)col * NN + m0 + mi * 16 + quad * 4], s4v, 8);
            }
#pragma unroll
            for (int mi = 0; mi < 2; ++mi)
#pragma unroll
                for (int r = 0; r < 4; ++r) {
                    float sv = acc[mi][r] * as;
                    float dv = acc[mi][r] * ad;
#pragma unroll
                    for (int off = 1; off < 16; off <<= 1) {
                        sv += __shfl_xor(sv, off);
                        dv += __shfl_xor(dv, off);
                    }
                    if (l15 == 0) {
                        const int row = m0 + mi * 16 + quad * 4 + r;
                        srcLp[(p2 * NN + row) * HH + h] = sv;
                        dstLp[(p2 * NN + row) * HH + h] = dv;
                    }
                }
        } else {
            float* Wv = WhVz + (size_t)z * BB * DG;
#pragma unroll
            for (int mi = 0; mi < 2; ++mi)
#pragma unroll
                for (int r = 0; r < 4; ++r)
                    Wv[(size_t)(m0 + mi * 16 + quad * 4 + r) * DG + col] = acc[mi][r];
            const int pv = p2 * 4 + z;
#pragma unroll
            for (int mi = 0; mi < 2; ++mi)
#pragma unroll
                for (int r = 0; r < 4; ++r) {
                    float sv = acc[mi][r] * as;
                    float dv = acc[mi][r] * ad;
#pragma unroll
                    for (int off = 1; off < 16; off <<= 1) {
                        sv += __shfl_xor(sv, off);
                        dv += __shfl_xor(dv, off);
                    }
                    if (l15 == 0) {
                        const int row = m0 + mi * 16 + quad * 4 + r;
                        srcVp[(pv * BB + row) * HH + h] = sv;
                        dstVp[(pv * BB + row) * HH + h] = dv;
                    }
                }
        }
    }
    __threadfence();
    grid.sync();

    // ================= S2: GAT with 8-b loop =================
    {
        const int h  = bid >> 5;
        const int it = (bid >> 3) & 3;
        const int bg = bid & 7;
        const int i0 = it * 64;
        const int w = t >> 6;
        const int lane = t & 63;
        const int l15 = lane & 15, quad = lane >> 4;
        const int g = lane >> 4, s = lane & 15;
        const int n0 = w * 32;

        // ---- one-time setup
        if (t < NN) {
            float dl = 0.f;
#pragma unroll
            for (int p = 0; p < 4; ++p) dl += dstLp[(p * NN + t) * HH + h];
            sh.s2.dls2[2 * t]     = __expf(dl);
            sh.s2.dls2[2 * t + 1] = __expf(ALPHA * dl);
        }
        if (t < 64) {
            float sl = 0.f;
#pragma unroll
            for (int p = 0; p < 4; ++p) sl += srcLp[(p * NN + i0 + t) * HH + h];
            sh.s2.esl[t]  = __expf(sl);
            sh.s2.easl[t] = __expf(ALPHA * sl);
            sh.s2.ensl[t] = __expf(-sl);
        }
        if (t < 128) {
            const int bi = t >> 4, p = t & 15;
            const int b = bg * 8 + bi;
            float v = srcVp[(p * BB + b) * HH + h] + dstVp[(p * BB + b) * HH + h];
#pragma unroll
            for (int off = 1; off < 16; off <<= 1) v += __shfl_xor(v, off);
            if (p == 0) sh.s2.cb[bi] = v;
        }
        { // adj bitmask: thread -> (row, 32-j word)
            const int row = t >> 3, wd = t & 7;
            const float* ab = adj + (size_t)(i0 + row) * NN + wd * 32;
            unsigned int m = 0;
#pragma unroll
            for (int k4 = 0; k4 < 8; ++k4) {
                const float4 v = *(const float4*)(ab + 4 * k4);
                m |= (v.x > 0.f ? 1u : 0u) << (4 * k4);
                m |= (v.y > 0.f ? 1u : 0u) << (4 * k4 + 1);
                m |= (v.z > 0.f ? 1u : 0u) << (4 * k4 + 2);
                m |= (v.w > 0.f ? 1u : 0u) << (4 * k4 + 3);
            }
            sh.s2.maskB[row][wd] = m;
        }
        // B fragments cached in registers for all 8 kc
        const unsigned short* wb = WhLbT + (size_t)(h * FF + n0 + l15) * NN + quad * 8;
        short8 bcr[8][2];
#pragma unroll
        for (int kc = 0; kc < 8; ++kc) {
            bcr[kc][0] = *(const short8*)(wb + kc * 32);
            bcr[kc][1] = *(const short8*)(wb + (size_t)16 * NN + kc * 32);
        }
        const float pqv0 = pool_q[h * FF + n0 + l15];
        const float pqv1 = pool_q[h * FF + n0 + 16 + l15];
        __syncthreads();

        for (int bi = 0; bi < 8; ++bi) {
            const int b = bg * 8 + bi;
            const float cbv = sh.s2.cb[bi];
            const float ec  = __expf(cbv);
            const float eac = __expf(ALPHA * cbv);
            const float enc = __expf(-cbv);
            float wv0 = 0.f, wv1 = 0.f;
#pragma unroll
            for (int z = 0; z < 4; ++z) {
                const float* Wv = WhVz + (size_t)z * BB * DG + (size_t)b * DG + h * FF + n0;
                wv0 += Wv[l15];
                wv1 += Wv[16 + l15];
            }
            // ---- phase 1
#pragma unroll
            for (int rr = 0; rr < 2; ++rr) {
                const int iloc = w * 8 + rr * 4 + g;
                const float Ai  = ec  * sh.s2.esl[iloc];
                const float Ci  = eac * sh.s2.easl[iloc];
                const float TEi = enc * sh.s2.ensl[iloc];
                float pr[16];
                float sum = 0.f;
#pragma unroll
                for (int jj = 0; jj < 8; ++jj) {
                    const int j0 = 2 * s + 32 * jj;
                    const unsigned int m = sh.s2.maskB[iloc][jj]; // broadcast
                    const float4 bd = *(const float4*)&sh.s2.dls2[2 * j0];
                    const bool g0 = bd.x > TEi;
                    const bool g1 = bd.z > TEi;
                    float p0 = (g0 ? Ai : Ci) * (g0 ? bd.x : bd.y);
                    float p1 = (g1 ? Ai : Ci) * (g1 ? bd.z : bd.w);
                    p0 = (m & (1u << (2 * s))) ? p0 : 0.f;
                    p1 = (m & (2u << (2 * s))) ? p1 : 0.f;
                    pr[2 * jj] = p0; pr[2 * jj + 1] = p1;
                    sum += p0 + p1;
                }
#pragma unroll
                for (int off = 1; off < 16; off <<= 1) sum += __shfl_xor(sum, off);
                if (s == 0) sh.s2.inv[iloc] = 1.0f / sum;
#pragma unroll
                for (int jj = 0; jj < 8; ++jj) {
                    const unsigned int pk =
                        ((unsigned int)f2bs(pr[2 * jj + 1]) << 16) | f2bs(pr[2 * jj]);
                    *(unsigned int*)&sh.s2.Pl[iloc][2 * s + 32 * jj] = pk;
                }
            }
            __syncthreads();

            // ---- phase 2: MFMA
            f32x4 acc[4][2];
#pragma unroll
            for (int mi = 0; mi < 4; ++mi)
#pragma unroll
                for (int ni = 0; ni < 2; ++ni) acc[mi][ni] = (f32x4){0.f, 0.f, 0.f, 0.f};
#pragma unroll
            for (int kc = 0; kc < 8; ++kc) {
                short8 a[4];
#pragma unroll
                for (int mi = 0; mi < 4; ++mi)
                    a[mi] = *(const short8*)&sh.s2.Pl[mi * 16 + l15][kc * 32 + quad * 8];
#pragma unroll
                for (int mi = 0; mi < 4; ++mi)
                    acc[mi][0] = __builtin_amdgcn_mfma_f32_16x16x32_bf16(a[mi], bcr[kc][0], acc[mi][0], 0, 0, 0);
#pragma unroll
                for (int mi = 0; mi < 4; ++mi)
                    acc[mi][1] = __builtin_amdgcn_mfma_f32_16x16x32_bf16(a[mi], bcr[kc][1], acc[mi][1], 0, 0, 0);
            }

            // ---- register epilogue
            float* psrow = ps_p + (size_t)(h * 8 + w) * BB * NN + (size_t)b * NN + i0;
#pragma unroll
            for (int mi = 0; mi < 4; ++mi)
#pragma unroll
                for (int r = 0; r < 4; ++r) {
                    const int row = mi * 16 + quad * 4 + r;
                    const float ivr = sh.s2.inv[row];
                    bf16* orow = outb + ((size_t)(b * NN + i0 + row)) * DG + h * FF + n0;
                    float x0 = fmaf(acc[mi][0][r], ivr, wv0);
                    float x1 = fmaf(acc[mi][1][r], ivr, wv1);
                    x0 = x0 > 0.f ? x0 : (__expf(x0) - 1.0f);
                    x1 = x1 > 0.f ? x1 : (__expf(x1) - 1.0f);
                    orow[l15]      = __float2bfloat16(x0);
                    orow[16 + l15] = __float2bfloat16(x1);
                    float dot = fmaf(x0, pqv0, x1 * pqv1);
#pragma unroll
                    for (int off = 1; off < 16; off <<= 1) dot += __shfl_xor(dot, off);
                    if (l15 == 0) psrow[row] = dot;
                }
            __syncthreads(); // Pl/inv reuse next bi
        }
    }
    __threadfence();
    grid.sync();

    // ================= S3a: pool + bias-init (2 units per block) =================
    {
        const int half = t >> 8;
        const int tt = t & 255;
        const int u = 2 * bid + half;   // 0..511
        const int dt = u & 7;
        const int b  = u >> 3;
        if (dt < 2) out[b * DE + dt * 256 + tt] = fcb[dt * 256 + tt];
        float v = 0.f;
#pragma unroll 8
        for (int sI = 0; sI < 64; ++sI)
            v += ps_p[(size_t)sI * BB * NN + (size_t)b * NN + tt];
        float m = v;
#pragma unroll
        for (int off = 32; off; off >>= 1) m = fmaxf(m, __shfl_xor(m, off));
        if ((tt & 63) == 0) sh.s3.redm[half][tt >> 6] = m;
        __syncthreads();
        m = fmaxf(fmaxf(sh.s3.redm[half][0], sh.s3.redm[half][1]),
                  fmaxf(sh.s3.redm[half][2], sh.s3.redm[half][3]));
        const float e = __expf(v - m);
        float sred = e;
#pragma unroll
        for (int off = 32; off; off >>= 1) sred += __shfl_xor(sred, off);
        if ((tt & 63) == 0) sh.s3.reds[half][tt >> 6] = sred;
        __syncthreads();
        sred = sh.s3.reds[half][0] + sh.s3.reds[half][1] + sh.s3.reds[half][2] + sh.s3.reds[half][3];
        sh.s3.wsm[half][tt] = e / sred;
        __syncthreads();
        const int d = dt * 256 + tt;
        float acc = 0.f;
        const bf16* base = outb + (size_t)b * NN * DG + d;
#pragma unroll 8
        for (int n = 0; n < NN; ++n)
            acc = fmaf(sh.s3.wsm[half][n], b2f(base[(size_t)n * DG]), acc);
        pooled[(size_t)b * DG + d] = acc;
    }
    __threadfence();
    grid.sync();

    // ================= S3b: out += pooled @ fcW (z=16 ksplit, atomic) =================
    {
        const int x  = bid & 7;         // n0 = x*64
        const int mm = (bid >> 3) & 1;  // m0 = mm*32
        const int z  = bid >> 4;        // 0..15
        const int n0f = x * 64;
        const int m0f = mm * 32;
        const int kb0 = z * 128;
        const int w = t >> 6;
        const int lane = t & 63;
        const int l15 = lane & 15, quad = lane >> 4;
#pragma unroll
        for (int p = 0; p < 2; ++p) {
            const int idx = t + 512 * p;       // 0..1023
            const int row = idx >> 5, c4 = idx & 31;
            const float4 v = *(const float4*)(pooled + (size_t)(m0f + row) * DG + kb0 + 4 * c4);
            unsigned short s4v[4] = {f2bs(v.x), f2bs(v.y), f2bs(v.z), f2bs(v.w)};
            __builtin_memcpy(&sh.s4.As[row][4 * c4], s4v, 8);
        }
#pragma unroll
        for (int p = 0; p < 4; ++p) {
            const int idx = t + 512 * p;       // 0..2047
            const int kk = idx >> 4, c4 = (idx & 15) * 4;
            const float4 v = *(const float4*)(fcW + (size_t)(kb0 + kk) * DE + n0f + c4);
            sh.s4.Bs[c4 + 0][kk] = f2bs(v.x);
            sh.s4.Bs[c4 + 1][kk] = f2bs(v.y);
            sh.s4.Bs[c4 + 2][kk] = f2bs(v.z);
            sh.s4.Bs[c4 + 3][kk] = f2bs(v.w);
        }
        __syncthreads();
        if (w < 4) {
            f32x4 acc[2];
            acc[0] = (f32x4){0.f, 0.f, 0.f, 0.f};
            acc[1] = (f32x4){0.f, 0.f, 0.f, 0.f};
#pragma unroll
            for (int kc = 0; kc < 4; ++kc) {
                const short8 bf = *(const short8*)&sh.s4.Bs[w * 16 + l15][kc * 32 + quad * 8];
#pragma unroll
                for (int mi = 0; mi < 2; ++mi) {
                    const short8 af = *(const short8*)&sh.s4.As[mi * 16 + l15][kc * 32 + quad * 8];
                    acc[mi] = __builtin_amdgcn_mfma_f32_16x16x32_bf16(af, bf, acc[mi], 0, 0, 0);
                }
            }
            const int col = n0f + w * 16 + l15;
#pragma unroll
            for (int mi = 0; mi < 2; ++mi)
#pragma unroll
                for (int r = 0; r < 4; ++r)
                    atomicAdd(&out[(size_t)(m0f + mi * 16 + quad * 4 + r) * DE + col], acc[mi][r]);
        }
    }
}

extern "C" void kernel_launch(void* const* d_in, const int* in_sizes, int n_in,
                              void* d_out, int out_size, void* d_ws, size_t ws_size,
                              hipStream_t stream) {
    (void)in_sizes; (void)n_in; (void)out_size; (void)ws_size;
    const float* visual = (const float*)d_in[0];
    const float* labels = (const float*)d_in[1];
    const float* adj    = (const float*)d_in[2];
    const float* Wg     = (const float*)d_in[3];
    const float* a_src  = (const float*)d_in[4];
    const float* a_dst  = (const float*)d_in[5];
    const float* pool_q = (const float*)d_in[6];
    const float* fcW    = (const float*)d_in[7];
    const float* fcb    = (const float*)d_in[8];
    float* out = (float*)d_out;

    float* ws_f   = (float*)d_ws;
    float* WhVz   = ws_f;                       // 4*64*2048
    float* srcLp  = WhVz + 4 * BB * DG;         // 4*256*8
    float* dstLp  = srcLp + 4 * NN * HH;        // 4*256*8
    float* srcVp  = dstLp + 4 * NN * HH;        // 16*64*8
    float* dstVp  = srcVp + 16 * BB * HH;       // 16*64*8
    float* ps_p   = dstVp + 16 * BB * HH;       // 64*64*256
    float* pooled = ps_p + 64 * BB * NN;        // 64*2048
    bf16*  outb   = (bf16*)(pooled + BB * DG);  // 64*256*2048 bf16
    unsigned short* WhLbT = (unsigned short*)(outb + (size_t)BB * NN * DG); // 2048*256

    void* args[] = {
        (void*)&labels, (void*)&visual, (void*)&Wg, (void*)&adj,
        (void*)&a_src, (void*)&a_dst, (void*)&pool_q, (void*)&fcW,
        (void*)&fcb, (void*)&out,
        (void*)&WhLbT, (void*)&WhVz, (void*)&srcLp, (void*)&dstLp,
        (void*)&srcVp, (void*)&dstVp, (void*)&ps_p, (void*)&pooled,
        (void*)&outb
    };
    hipLaunchCooperativeKernel((void*)k_mega, dim3(256), dim3(512), args, 0, stream);
}

// Round 14
// 192.248 us; speedup vs baseline: 2.0673x; 2.0673x over previous
//
#include <hip/hip_runtime.h>
#include <hip/hip_bf16.h>
#include <math.h>

#define BB 64
#define NN 256
#define D_VIS 2048
#define D_LBL 512
#define HH 8
#define FF 256
#define DG 2048
#define DE 512
#define ALPHA 0.2f
#define PSTRIDE 264

using bf16 = __hip_bfloat16;
using short8 = __attribute__((ext_vector_type(8))) short;
using f32x4  = __attribute__((ext_vector_type(4))) float;
__device__ __forceinline__ float b2f(bf16 x) { return __bfloat162float(x); }
__device__ __forceinline__ unsigned short f2bs(float x) {
    bf16 h = __float2bfloat16(x);
    unsigned short u;
    __builtin_memcpy(&u, &h, 2);
    return u;
}

// ---------------- fused Wh GEMM (identical to R12)
__global__ void __launch_bounds__(256) k_wh(const float* __restrict__ labels,
                                            const float* __restrict__ visual,
                                            const float* __restrict__ Wg,
                                            unsigned short* __restrict__ WhLbT,
                                            float* __restrict__ WhVz,
                                            const float* __restrict__ aSrc,
                                            const float* __restrict__ aDst,
                                            float* __restrict__ srcLp,
                                            float* __restrict__ dstLp,
                                            float* __restrict__ srcVp,
                                            float* __restrict__ dstVp) {
    __shared__ unsigned short As[32][72];
    __shared__ unsigned short Bs[64][72];
    const int t = threadIdx.x;
    const int w = t >> 6;
    const int lane = t & 63;
    const int l15 = lane & 15, quad = lane >> 4;
    const int n0 = blockIdx.x * 64;
    const int p2 = blockIdx.x & 3;
    const int y = blockIdx.y;
    const bool isL = (y < 8);
    const int q = y - 8;
    const int m0  = isL ? y * 32 : (q & 1) * 32;
    const int z   = isL ? 0 : (q >> 1);
    const int kb0 = z * 512;
    const float* A = isL ? labels : visual;
    const int lda  = isL ? D_LBL : D_VIS;
    const float* Wb = Wg + (isL ? 0 : (size_t)D_LBL * DG);

    f32x4 acc[2];
    acc[0] = (f32x4){0.f, 0.f, 0.f, 0.f};
    acc[1] = (f32x4){0.f, 0.f, 0.f, 0.f};

    for (int kc = 0; kc < 8; ++kc) {
        const int kb = kb0 + kc * 64;
#pragma unroll
        for (int p = 0; p < 2; ++p) {
            const int idx = t + 256 * p;
            const int r = idx >> 4, q4 = idx & 15;
            const float4 v = *(const float4*)(A + (size_t)(m0 + r) * lda + kb + 4 * q4);
            unsigned short s4[4] = {f2bs(v.x), f2bs(v.y), f2bs(v.z), f2bs(v.w)};
            __builtin_memcpy(&As[r][4 * q4], s4, 8);
        }
#pragma unroll
        for (int p = 0; p < 4; ++p) {
            const int kk = (t >> 4) + 16 * p;
            const int c4 = (t & 15) * 4;
            const float4 v = *(const float4*)(Wb + (size_t)(kb + kk) * DG + n0 + c4);
            Bs[c4 + 0][kk] = f2bs(v.x);
            Bs[c4 + 1][kk] = f2bs(v.y);
            Bs[c4 + 2][kk] = f2bs(v.z);
            Bs[c4 + 3][kk] = f2bs(v.w);
        }
        __syncthreads();
#pragma unroll
        for (int ks = 0; ks < 2; ++ks) {
            const short8 bf = *(const short8*)&Bs[w * 16 + l15][ks * 32 + quad * 8];
#pragma unroll
            for (int mi = 0; mi < 2; ++mi) {
                const short8 af = *(const short8*)&As[mi * 16 + l15][ks * 32 + quad * 8];
                acc[mi] = __builtin_amdgcn_mfma_f32_16x16x32_bf16(af, bf, acc[mi], 0, 0, 0);
            }
        }
        __syncthreads();
    }
    const int col = n0 + w * 16 + l15;
    const int h = col >> 8;
    const float as = aSrc[col], ad = aDst[col];
    if (isL) {
#pragma unroll
        for (int mi = 0; mi < 2; ++mi) {
            unsigned short s4[4];
#pragma unroll
            for (int r = 0; r < 4; ++r) s4[r] = f2bs(acc[mi][r]);
            __builtin_memcpy(&WhLbT[(size_t)col * NN + m0 + mi * 16 + quad * 4], s4, 8);
        }
#pragma unroll
        for (int mi = 0; mi < 2; ++mi)
#pragma unroll
            for (int r = 0; r < 4; ++r) {
                float sv = acc[mi][r] * as;
                float dv = acc[mi][r] * ad;
#pragma unroll
                for (int off = 1; off < 16; off <<= 1) {
                    sv += __shfl_xor(sv, off);
                    dv += __shfl_xor(dv, off);
                }
                if (l15 == 0) {
                    const int row = m0 + mi * 16 + quad * 4 + r;
                    srcLp[(p2 * NN + row) * HH + h] = sv;
                    dstLp[(p2 * NN + row) * HH + h] = dv;
                }
            }
    } else {
        float* Wv = WhVz + (size_t)z * BB * DG;
#pragma unroll
        for (int mi = 0; mi < 2; ++mi)
#pragma unroll
            for (int r = 0; r < 4; ++r)
                Wv[(size_t)(m0 + mi * 16 + quad * 4 + r) * DG + col] = acc[mi][r];
        const int pv = p2 * 4 + z;
#pragma unroll
        for (int mi = 0; mi < 2; ++mi)
#pragma unroll
            for (int r = 0; r < 4; ++r) {
                float sv = acc[mi][r] * as;
                float dv = acc[mi][r] * ad;
#pragma unroll
                for (int off = 1; off < 16; off <<= 1) {
                    sv += __shfl_xor(sv, off);
                    dv += __shfl_xor(dv, off);
                }
                if (l15 == 0) {
                    const int row = m0 + mi * 16 + quad * 4 + r;
                    srcVp[(pv * BB + row) * HH + h] = sv;
                    dstVp[(pv * BB + row) * HH + h] = dv;
                }
            }
    }
}

// ---------------- MFMA GAT with 2-batch loop + adj bitmask.
// grid (bg,h,it) = 32*8*4 = 1024 blocks, 512 thr (8 waves). LDS ~38.9 KB (4 blk/CU).
__global__ void __launch_bounds__(512, 4) k_gat(const unsigned short* __restrict__ WhLbT,
                                                const float* __restrict__ WhVz,
                                                const float* __restrict__ srcLp,
                                                const float* __restrict__ dstLp,
                                                const float* __restrict__ srcVp,
                                                const float* __restrict__ dstVp,
                                                const float* __restrict__ adj,
                                                const float* __restrict__ pool_q,
                                                bf16* __restrict__ outb,
                                                float* __restrict__ ps_p) {
    const int bid = blockIdx.x;
    const int it = bid & 3;
    const int h  = (bid >> 2) & 7;
    const int bg = bid >> 5;          // 0..31, batches 2bg, 2bg+1
    const int i0 = it * 64;
    const int t = threadIdx.x;
    const int w = t >> 6;
    const int lane = t & 63;
    const int l15 = lane & 15, quad = lane >> 4;
    const int g = lane >> 4, s = lane & 15;

    __shared__ __align__(16) unsigned short Pl[64][PSTRIDE]; // 33792 B
    __shared__ __align__(16) float dls2[2 * NN];             // 2048 B
    __shared__ float esl[64], easl[64], ensl[64], inv[64];   // 1024 B
    __shared__ float cb[2];
    __shared__ unsigned int maskB[64][8];                    // 2048 B

    // ---- one-time setup (shared across both batches)
    if (t < NN) {
        float dl = 0.f;
#pragma unroll
        for (int p = 0; p < 4; ++p) dl += dstLp[(p * NN + t) * HH + h];
        dls2[2 * t]     = __expf(dl);
        dls2[2 * t + 1] = __expf(ALPHA * dl);
    }
    if (t < 64) {
        float sl = 0.f;
#pragma unroll
        for (int p = 0; p < 4; ++p) sl += srcLp[(p * NN + i0 + t) * HH + h];
        esl[t]  = __expf(sl);
        easl[t] = __expf(ALPHA * sl);
        ensl[t] = __expf(-sl);
    }
    if (t < 32) {
        const int bi = t >> 4, p = t & 15;
        const int b = bg * 2 + bi;
        float v = srcVp[(p * BB + b) * HH + h] + dstVp[(p * BB + b) * HH + h];
#pragma unroll
        for (int off = 1; off < 16; off <<= 1) v += __shfl_xor(v, off);
        if (p == 0) cb[bi] = v;
    }
    { // adj bitmask: thread -> (row, 32-j word)
        const int row = t >> 3, wd = t & 7;
        const float* ab = adj + (size_t)(i0 + row) * NN + wd * 32;
        unsigned int m = 0;
#pragma unroll
        for (int k4 = 0; k4 < 8; ++k4) {
            const float4 v = *(const float4*)(ab + 4 * k4);
            m |= (v.x > 0.f ? 1u : 0u) << (4 * k4);
            m |= (v.y > 0.f ? 1u : 0u) << (4 * k4 + 1);
            m |= (v.z > 0.f ? 1u : 0u) << (4 * k4 + 2);
            m |= (v.w > 0.f ? 1u : 0u) << (4 * k4 + 3);
        }
        maskB[row][wd] = m;
    }
    const int n0 = w * 32;
    const float pqv0 = pool_q[h * FF + n0 + l15];
    const float pqv1 = pool_q[h * FF + n0 + 16 + l15];
    const unsigned short* wb = WhLbT + (size_t)(h * FF + n0 + l15) * NN + quad * 8;
    __syncthreads();

    for (int bi = 0; bi < 2; ++bi) {
        const int b = bg * 2 + bi;
        const float cbv = cb[bi];
        const float ec  = __expf(cbv);
        const float eac = __expf(ALPHA * cbv);
        const float enc = __expf(-cbv);
        float wv0 = 0.f, wv1 = 0.f;
#pragma unroll
        for (int z = 0; z < 4; ++z) {
            const float* Wv = WhVz + (size_t)z * BB * DG + (size_t)b * DG + h * FF + n0;
            wv0 += Wv[l15];
            wv1 += Wv[16 + l15];
        }
        // ---- phase 1: masked exp via factorization + bitmask
#pragma unroll
        for (int rr = 0; rr < 2; ++rr) {
            const int iloc = w * 8 + rr * 4 + g;
            const float Ai  = ec  * esl[iloc];
            const float Ci  = eac * easl[iloc];
            const float TEi = enc * ensl[iloc];
            float pr[16];
            float sum = 0.f;
#pragma unroll
            for (int jj = 0; jj < 8; ++jj) {
                const int j0 = 2 * s + 32 * jj;
                const unsigned int m = maskB[iloc][jj]; // LDS broadcast
                const float4 bd = *(const float4*)&dls2[2 * j0];
                const bool g0 = bd.x > TEi;
                const bool g1 = bd.z > TEi;
                float p0 = (g0 ? Ai : Ci) * (g0 ? bd.x : bd.y);
                float p1 = (g1 ? Ai : Ci) * (g1 ? bd.z : bd.w);
                p0 = (m & (1u << (2 * s))) ? p0 : 0.f;
                p1 = (m & (2u << (2 * s))) ? p1 : 0.f;
                pr[2 * jj] = p0; pr[2 * jj + 1] = p1;
                sum += p0 + p1;
            }
#pragma unroll
            for (int off = 1; off < 16; off <<= 1) sum += __shfl_xor(sum, off);
            if (s == 0) inv[iloc] = 1.0f / sum;
#pragma unroll
            for (int jj = 0; jj < 8; ++jj) {
                const unsigned int pk =
                    ((unsigned int)f2bs(pr[2 * jj + 1]) << 16) | f2bs(pr[2 * jj]);
                *(unsigned int*)&Pl[iloc][2 * s + 32 * jj] = pk;
            }
        }
        __syncthreads();

        // ---- phase 2: MFMA with B prefetch chain (R12 pattern)
        f32x4 acc[4][2];
#pragma unroll
        for (int mi = 0; mi < 4; ++mi)
#pragma unroll
            for (int ni = 0; ni < 2; ++ni) acc[mi][ni] = (f32x4){0.f, 0.f, 0.f, 0.f};

        short8 bc0 = *(const short8*)(wb);
        short8 bc1 = *(const short8*)(wb + (size_t)16 * NN);
#pragma unroll
        for (int kc = 0; kc < 8; ++kc) {
            short8 bn0, bn1;
            if (kc < 7) {
                bn0 = *(const short8*)(wb + (kc + 1) * 32);
                bn1 = *(const short8*)(wb + (size_t)16 * NN + (kc + 1) * 32);
            }
            short8 a[4];
#pragma unroll
            for (int mi = 0; mi < 4; ++mi)
                a[mi] = *(const short8*)&Pl[mi * 16 + l15][kc * 32 + quad * 8];
#pragma unroll
            for (int mi = 0; mi < 4; ++mi)
                acc[mi][0] = __builtin_amdgcn_mfma_f32_16x16x32_bf16(a[mi], bc0, acc[mi][0], 0, 0, 0);
#pragma unroll
            for (int mi = 0; mi < 4; ++mi)
                acc[mi][1] = __builtin_amdgcn_mfma_f32_16x16x32_bf16(a[mi], bc1, acc[mi][1], 0, 0, 0);
            bc0 = bn0; bc1 = bn1;
        }

        // ---- register epilogue
        float* psrow = ps_p + (size_t)(h * 8 + w) * BB * NN + (size_t)b * NN + i0;
#pragma unroll
        for (int mi = 0; mi < 4; ++mi)
#pragma unroll
            for (int r = 0; r < 4; ++r) {
                const int row = mi * 16 + quad * 4 + r;
                const float ivr = inv[row];
                bf16* orow = outb + ((size_t)(b * NN + i0 + row)) * DG + h * FF + n0;
                float x0 = fmaf(acc[mi][0][r], ivr, wv0);
                float x1 = fmaf(acc[mi][1][r], ivr, wv1);
                x0 = x0 > 0.f ? x0 : (__expf(x0) - 1.0f);
                x1 = x1 > 0.f ? x1 : (__expf(x1) - 1.0f);
                orow[l15]      = __float2bfloat16(x0);
                orow[16 + l15] = __float2bfloat16(x1);
                float dot = fmaf(x0, pqv0, x1 * pqv1);
#pragma unroll
                for (int off = 1; off < 16; off <<= 1) dot += __shfl_xor(dot, off);
                if (l15 == 0) psrow[row] = dot;
            }
        __syncthreads(); // Pl/inv reused next bi
    }
}

// ---------------- k_pool (identical to R12)
__global__ void __launch_bounds__(256) k_pool(const bf16* __restrict__ outb,
                                              const float* __restrict__ ps_p,
                                              float* __restrict__ pooled,
                                              const float* __restrict__ fcb,
                                              float* __restrict__ out) {
    const int dt = blockIdx.x;
    const int b  = blockIdx.y;
    const int t  = threadIdx.x;
    if (dt < 2) out[b * DE + dt * 256 + t] = fcb[dt * 256 + t];
    __shared__ float wsm[NN];
    __shared__ float redm[4];
    __shared__ float reds[4];
    float v = 0.f;
#pragma unroll 8
    for (int s = 0; s < 64; ++s)
        v += ps_p[(size_t)s * BB * NN + (size_t)b * NN + t];
    float m = v;
#pragma unroll
    for (int off = 32; off; off >>= 1) m = fmaxf(m, __shfl_xor(m, off));
    if ((t & 63) == 0) redm[t >> 6] = m;
    __syncthreads();
    m = fmaxf(fmaxf(redm[0], redm[1]), fmaxf(redm[2], redm[3]));
    const float e = __expf(v - m);
    float s = e;
#pragma unroll
    for (int off = 32; off; off >>= 1) s += __shfl_xor(s, off);
    if ((t & 63) == 0) reds[t >> 6] = s;
    __syncthreads();
    s = reds[0] + reds[1] + reds[2] + reds[3];
    wsm[t] = e / s;
    __syncthreads();
    const int d = dt * 256 + t;
    float acc = 0.f;
    const bf16* base = outb + (size_t)b * NN * DG + d;
#pragma unroll 8
    for (int n = 0; n < NN; ++n)
        acc = fmaf(wsm[n], b2f(base[(size_t)n * DG]), acc);
    pooled[(size_t)b * DG + d] = acc;
}

// ---------------- fc GEMM (identical to R12)
__global__ void __launch_bounds__(256) k_mgemm(const float* __restrict__ A, int lda,
                                               const float* __restrict__ W, int ldw,
                                               float* __restrict__ C, int ldc,
                                               int kSlice, int kIters) {
    __shared__ unsigned short As[32][72];
    __shared__ unsigned short Bs[64][72];
    const int t = threadIdx.x;
    const int w = t >> 6;
    const int lane = t & 63;
    const int l15 = lane & 15, quad = lane >> 4;
    const int n0 = blockIdx.x * 64;
    const int m0 = blockIdx.y * 32;
    const int kb0 = blockIdx.z * kSlice;
    f32x4 acc[2];
    acc[0] = (f32x4){0.f, 0.f, 0.f, 0.f};
    acc[1] = (f32x4){0.f, 0.f, 0.f, 0.f};
    for (int kc = 0; kc < kIters; ++kc) {
        const int kb = kb0 + kc * 64;
#pragma unroll
        for (int p = 0; p < 2; ++p) {
            const int idx = t + 256 * p;
            const int r = idx >> 4, q4 = idx & 15;
            const float4 v = *(const float4*)(A + (size_t)(m0 + r) * lda + kb + 4 * q4);
            unsigned short s4[4] = {f2bs(v.x), f2bs(v.y), f2bs(v.z), f2bs(v.w)};
            __builtin_memcpy(&As[r][4 * q4], s4, 8);
        }
#pragma unroll
        for (int p = 0; p < 4; ++p) {
            const int kk = (t >> 4) + 16 * p;
            const int c4 = (t & 15) * 4;
            const float4 v = *(const float4*)(W + (size_t)(kb + kk) * ldw + n0 + c4);
            Bs[c4 + 0][kk] = f2bs(v.x);
            Bs[c4 + 1][kk] = f2bs(v.y);
            Bs[c4 + 2][kk] = f2bs(v.z);
            Bs[c4 + 3][kk] = f2bs(v.w);
        }
        __syncthreads();
#pragma unroll
        for (int ks = 0; ks < 2; ++ks) {
            const short8 bf = *(const short8*)&Bs[w * 16 + l15][ks * 32 + quad * 8];
#pragma unroll
            for (int mi = 0; mi < 2; ++mi) {
                const short8 af = *(const short8*)&As[mi * 16 + l15][ks * 32 + quad * 8];
                acc[mi] = __builtin_amdgcn_mfma_f32_16x16x32_bf16(af, bf, acc[mi], 0, 0, 0);
            }
        }
        __syncthreads();
    }
    const int col = n0 + w * 16 + l15;
#pragma unroll
    for (int mi = 0; mi < 2; ++mi)
#pragma unroll
        for (int r = 0; r < 4; ++r)
            atomicAdd(&C[(size_t)(m0 + mi * 16 + quad * 4 + r) * ldc + col], acc[mi][r]);
}

extern "C" void kernel_launch(void* const* d_in, const int* in_sizes, int n_in,
                              void* d_out, int out_size, void* d_ws, size_t ws_size,
                              hipStream_t stream) {
    (void)in_sizes; (void)n_in; (void)out_size; (void)ws_size;
    const float* visual = (const float*)d_in[0];
    const float* labels = (const float*)d_in[1];
    const float* adj    = (const float*)d_in[2];
    const float* Wg     = (const float*)d_in[3];
    const float* a_src  = (const float*)d_in[4];
    const float* a_dst  = (const float*)d_in[5];
    const float* pool_q = (const float*)d_in[6];
    const float* fcW    = (const float*)d_in[7];
    const float* fcb    = (const float*)d_in[8];
    float* out = (float*)d_out;

    float* ws_f   = (float*)d_ws;
    float* WhVz   = ws_f;                       // 4*64*2048
    float* srcLp  = WhVz + 4 * BB * DG;         // 4*256*8
    float* dstLp  = srcLp + 4 * NN * HH;        // 4*256*8
    float* srcVp  = dstLp + 4 * NN * HH;        // 16*64*8
    float* dstVp  = srcVp + 16 * BB * HH;       // 16*64*8
    float* ps_p   = dstVp + 16 * BB * HH;       // 64*64*256
    float* pooled = ps_p + 64 * BB * NN;        // 64*2048
    bf16*  outb   = (bf16*)(pooled + BB * DG);  // 64*256*2048 bf16
    unsigned short* WhLbT = (unsigned short*)(outb + (size_t)BB * NN * DG); // 2048*256

    k_wh<<<dim3(DG / 64, 16), 256, 0, stream>>>(labels, visual, Wg, WhLbT, WhVz,
                                                a_src, a_dst, srcLp, dstLp, srcVp, dstVp);

    k_gat<<<32 * HH * 4, 512, 0, stream>>>(WhLbT, WhVz, srcLp, dstLp, srcVp, dstVp,
                                           adj, pool_q, outb, ps_p);

    k_pool<<<dim3(8, BB), 256, 0, stream>>>(outb, ps_p, pooled, fcb, out);

    k_mgemm<<<dim3(DE / 64, BB / 32, 8), 256, 0, stream>>>(
        pooled, DG, fcW, DE, out, DE, 256, 4);
}